// Round 1
// baseline (885.068 us; speedup 1.0000x reference)
//
#include <hip/hip_runtime.h>
#include <math.h>

#define NB   2
#define N1S  4096
#define N2S  8192
#define CC   64
#define CIN  67
#define KK   16
#define TILE 2048
#define QPB  4

struct KnnLds { float xs[TILE], ys[TILE], zs[TILE], ss[TILE]; };
struct GateLds {
  float feat[QPB][KK][68];   // [point][k][cin], rows 16B-aligned (68*4=272)
  float bufA[QPB][KK][CC];   // r0 activations, then r*p1
  float p1s[QPB][CC];
  float vbuf[QPB][CC];       // zmax then hmax
};
union alignas(16) SharedU { KnnLds knn; GateLds g; };

__device__ __forceinline__ float lrelu(float v){ return v > 0.f ? v : 0.1f*v; }
__device__ __forceinline__ float sigm(float v){ return 1.f/(1.f + __expf(-v)); }
__device__ __forceinline__ float tanh_(float v){ return 1.f - 2.f/(__expf(2.f*v) + 1.f); }

__device__ __forceinline__ float dot67(const float* __restrict__ wrow, const float* fr) {
  float a0 = 0.f, a1 = 0.f;
  #pragma unroll
  for (int c4 = 0; c4 < 16; c4++) {
    float4 f = *(const float4*)&fr[c4*4];
    a0 += wrow[c4*4+0]*f.x + wrow[c4*4+1]*f.y;
    a1 += wrow[c4*4+2]*f.z + wrow[c4*4+3]*f.w;
  }
  a0 += wrow[64]*fr[64] + wrow[66]*fr[66];
  a1 += wrow[65]*fr[65];
  return a0 + a1;
}
__device__ __forceinline__ float dot64(const float* __restrict__ wrow, const float* fr) {
  float a0 = 0.f, a1 = 0.f;
  #pragma unroll
  for (int c4 = 0; c4 < 16; c4++) {
    float4 f = *(const float4*)&fr[c4*4];
    a0 += wrow[c4*4+0]*f.x + wrow[c4*4+1]*f.y;
    a1 += wrow[c4*4+2]*f.z + wrow[c4*4+3]*f.w;
  }
  return a0 + a1;
}
__device__ __forceinline__ void ldrow67(const float* __restrict__ wm, int o, float* wrow){
  #pragma unroll
  for (int c = 0; c < CIN; c++) wrow[c] = wm[o*CIN + c];
}
__device__ __forceinline__ void ldrow64(const float* __restrict__ wm, int o, float* wrow){
  #pragma unroll
  for (int c4 = 0; c4 < 16; c4++) {
    float4 t = *(const float4*)&wm[o*CC + c4*4];
    wrow[c4*4] = t.x; wrow[c4*4+1] = t.y; wrow[c4*4+2] = t.z; wrow[c4*4+3] = t.w;
  }
}

__global__ __launch_bounds__(256) void transpose_p2(const float* __restrict__ src, float* __restrict__ dst){
  __shared__ float t[64][65];
  int b = blockIdx.y; int j0 = blockIdx.x*64;
  int tx = threadIdx.x & 63; int r4 = threadIdx.x >> 6;
  #pragma unroll
  for (int c = r4; c < 64; c += 4) t[c][tx] = src[((size_t)b*CC + c)*N2S + j0 + tx];
  __syncthreads();
  #pragma unroll
  for (int j = r4; j < 64; j += 4) dst[((size_t)b*N2S + j0 + j)*CC + tx] = t[tx][j];
}

__global__ __launch_bounds__(256) void gru_fused(
    const float* __restrict__ xyz1, const float* __restrict__ xyz2,
    const float* __restrict__ points1, const float* __restrict__ p2g,
    const int sJ, const int sC,
    const float* __restrict__ w_r0, const float* __restrict__ b_r0,
    const float* __restrict__ w_r1, const float* __restrict__ b_r1,
    const float* __restrict__ w_z0, const float* __restrict__ b_z0,
    const float* __restrict__ w_z1, const float* __restrict__ b_z1,
    const float* __restrict__ w_h0, const float* __restrict__ b_h0,
    const float* __restrict__ w_h1, const float* __restrict__ b_h1,
    const float* __restrict__ w_fr, const float* __restrict__ w_fz,
    const float* __restrict__ w_fro,
    float* __restrict__ out)
{
  __shared__ SharedU L;
  __shared__ int knnidx[QPB][KK];
  const int tid = threadIdx.x;
  const int w = tid >> 6, lane = tid & 63;
  const int qid = blockIdx.x*QPB + w;
  const int b = qid >> 12, n = qid & (N1S-1);
  const float* __restrict__ X2 = xyz2 + (size_t)b*3*N2S;
  const float qx = xyz1[((size_t)b*3+0)*N1S + n];
  const float qy = xyz1[((size_t)b*3+1)*N1S + n];
  const float qz = xyz1[((size_t)b*3+2)*N1S + n];
  const float s1 = (qx*qx + qy*qy) + qz*qz;

  // ---------------- phase 1: KNN (wave per query, ballot + serial shfl-insert) -------------
  float listd = INFINITY; int listi = 0; float kth = INFINITY;
  for (int t0 = 0; t0 < N2S; t0 += TILE) {
    __syncthreads();
    for (int i = tid; i < TILE; i += 256) {
      float x = X2[t0+i], y = X2[N2S+t0+i], z = X2[2*N2S+t0+i];
      L.knn.xs[i] = x; L.knn.ys[i] = y; L.knn.zs[i] = z; L.knn.ss[i] = (x*x + y*y) + z*z;
    }
    __syncthreads();
    for (int c0 = 0; c0 < TILE; c0 += 64) {
      const int ci = c0 + lane;
      // match reference formula: (|x1|^2 + |x2|^2) - 2*dot
      float d = (s1 + L.knn.ss[ci]) - 2.f*((qx*L.knn.xs[ci] + qy*L.knn.ys[ci]) + qz*L.knn.zs[ci]);
      unsigned long long vote = __ballot(d < kth);
      while (vote) {
        const int src = (int)__builtin_ctzll(vote);
        vote &= vote - 1;
        const float dv = __shfl(d, src);
        if (dv < kth) {                      // uniform branch (dv, kth uniform)
          const int iv = t0 + c0 + src;
          const float ud = __shfl_up(listd, 1);
          const int   ui = __shfl_up(listi, 1);
          const bool cm = dv < listd;        // suffix mask (list sorted ascending)
          const bool cp = (lane > 0) && (dv < ud);
          listd = cm ? (cp ? ud : dv) : listd;
          listi = cm ? (cp ? ui : iv) : listi;
          kth = __shfl(listd, KK-1);
        }
      }
    }
  }
  if (lane < KK) knnidx[w][lane] = listi;
  __syncthreads();   // all waves done reading L.knn before L.g writes below

  // ---------------- phase 2: gather ----------------
  const float* __restrict__ P2 = p2g + (size_t)b*CC*N2S;
  const float p1o = points1[((size_t)b*CC + lane)*N1S + n];
  L.g.p1s[w][lane] = p1o;
  for (int k = 0; k < KK; k++) {
    const int j = knnidx[w][k];
    L.g.feat[w][k][lane] = P2[(size_t)j*sJ + (size_t)lane*sC];
    if (lane < 3)
      L.g.feat[w][k][CC+lane] = X2[(size_t)lane*N2S + j] - xyz1[((size_t)b*3+lane)*N1S + n];
  }
  __syncthreads();

  // ---------------- phase 3: gates (thread = out channel, wave = point) -------------------
  // fuse terms: fr = w_fuse_r[o,:]·p1,  fz = w_fuse_z[o,:]·p1
  float frv = 0.f, fzv = 0.f;
  {
    #pragma unroll
    for (int c4 = 0; c4 < 16; c4++) {
      float4 p = *(const float4*)&L.g.p1s[w][c4*4];
      float4 a = *(const float4*)&w_fr[lane*CC + c4*4];
      float4 g = *(const float4*)&w_fz[lane*CC + c4*4];
      frv += a.x*p.x + a.y*p.y + a.z*p.z + a.w*p.w;
      fzv += g.x*p.x + g.y*p.y + g.z*p.z + g.w*p.w;
    }
  }

  // r0: lrelu(w_r0·feat + b_r0 + fr)  -> bufA[k][o]
  {
    float wrow[CIN]; ldrow67(w_r0, lane, wrow);
    const float bb = b_r0[lane] + frv;
    for (int k = 0; k < KK; k++)
      L.g.bufA[w][k][lane] = lrelu(bb + dot67(wrow, &L.g.feat[w][k][0]));
  }
  __syncthreads();

  // r1: sigmoid(w_r1·r0 + b_r1); immediately overwrite bufA row with r*p1 (wave-local, in-order)
  {
    float wrow[CC]; ldrow64(w_r1, lane, wrow);
    const float bb = b_r1[lane];
    for (int k = 0; k < KK; k++) {
      float rgk = sigm(bb + dot64(wrow, &L.g.bufA[w][k][0]));
      L.g.bufA[w][k][lane] = rgk * p1o;
    }
  }
  __syncthreads();

  // z0 + max over k
  {
    float wrow[CIN]; ldrow67(w_z0, lane, wrow);
    const float bb = b_z0[lane] + fzv;
    float zm = -INFINITY;
    for (int k = 0; k < KK; k++)
      zm = fmaxf(zm, lrelu(bb + dot67(wrow, &L.g.feat[w][k][0])));
    L.g.vbuf[w][lane] = zm;
  }
  __syncthreads();
  float zg;
  {
    float wrow[CC]; ldrow64(w_z1, lane, wrow);
    zg = sigm(b_z1[lane] + dot64(wrow, &L.g.vbuf[w][0]));
  }

  // p1e[k] = w_fuse_ro·(r*p1)  (bufA now holds r*p1)
  float p1e[KK];
  {
    float wrow[CC]; ldrow64(w_fro, lane, wrow);
    #pragma unroll
    for (int k = 0; k < KK; k++)
      p1e[k] = dot64(wrow, &L.g.bufA[w][k][0]);
  }
  // h0 + max over k
  {
    float wrow[CIN]; ldrow67(w_h0, lane, wrow);
    const float bb = b_h0[lane];
    float hm = -INFINITY;
    #pragma unroll
    for (int k = 0; k < KK; k++)
      hm = fmaxf(hm, lrelu(bb + p1e[k] + dot67(wrow, &L.g.feat[w][k][0])));
    L.g.vbuf[w][lane] = hm;    // safe: z1's vbuf reads precede in wave program order
  }
  __syncthreads();
  float hg;
  {
    float wrow[CC]; ldrow64(w_h1, lane, wrow);
    hg = tanh_(b_h1[lane] + dot64(wrow, &L.g.vbuf[w][0]));
  }
  out[((size_t)b*CC + lane)*N1S + n] = (1.f - zg)*p1o + zg*hg;
}

extern "C" void kernel_launch(void* const* d_in, const int* in_sizes, int n_in,
                              void* d_out, int out_size, void* d_ws, size_t ws_size,
                              hipStream_t stream) {
  const float* xyz1    = (const float*)d_in[0];
  const float* xyz2    = (const float*)d_in[1];
  const float* points1 = (const float*)d_in[2];
  const float* points2 = (const float*)d_in[3];
  const float* w_r0 = (const float*)d_in[4];
  const float* b_r0 = (const float*)d_in[5];
  const float* w_r1 = (const float*)d_in[6];
  const float* b_r1 = (const float*)d_in[7];
  const float* w_z0 = (const float*)d_in[8];
  const float* b_z0 = (const float*)d_in[9];
  const float* w_z1 = (const float*)d_in[10];
  const float* b_z1 = (const float*)d_in[11];
  const float* w_h0 = (const float*)d_in[12];
  const float* b_h0 = (const float*)d_in[13];
  const float* w_h1 = (const float*)d_in[14];
  const float* b_h1 = (const float*)d_in[15];
  const float* w_fr  = (const float*)d_in[16];
  const float* w_fz  = (const float*)d_in[17];
  const float* w_fro = (const float*)d_in[18];
  float* out = (float*)d_out;

  const size_t p2t_bytes = (size_t)NB*N2S*CC*sizeof(float);
  const bool useT = (ws_size >= p2t_bytes);
  const float* p2g = points2; int sJ = 1, sC = N2S;
  if (useT) {
    float* p2t = (float*)d_ws;
    transpose_p2<<<dim3(N2S/64, NB), dim3(256), 0, stream>>>(points2, p2t);
    p2g = p2t; sJ = CC; sC = 1;
  }
  gru_fused<<<dim3(NB*N1S/QPB), dim3(256), 0, stream>>>(
      xyz1, xyz2, points1, p2g, sJ, sC,
      w_r0, b_r0, w_r1, b_r1, w_z0, b_z0, w_z1, b_z1,
      w_h0, b_h0, w_h1, b_h1, w_fr, w_fz, w_fro, out);
}

// Round 2
// 539.607 us; speedup vs baseline: 1.6402x; 1.6402x over previous
//
#include <hip/hip_runtime.h>
#include <math.h>

#define NB    2
#define N1S   4096
#define N2S   8192
#define CC    64
#define CIN   67
#define KK    16
#define QPB   4
#define KTILE 1024

// ---- ws layout (float indices for wT; byte offsets below) ----
#define WT_R0_OFF  0
#define WT_Z0_OFF  (68*64)
#define WT_H0_OFF  (2*68*64)
#define WT_R1_OFF  (3*68*64)
#define WT_Z1_OFF  (3*68*64 + 1*64*64)
#define WT_H1_OFF  (3*68*64 + 2*64*64)
#define WT_FR_OFF  (3*68*64 + 3*64*64)
#define WT_FZ_OFF  (3*68*64 + 4*64*64)
#define WT_FRO_OFF (3*68*64 + 5*64*64)
#define WT_FLOATS  (3*68*64 + 6*64*64)          // 37632 floats
#define IDX_OFF_B  (WT_FLOATS*4)                // 150528 B
#define IDX_BYTES  (NB*N1S*KK*4)                // 524288 B
#define P2T_OFF_B  (IDX_OFF_B + IDX_BYTES)      // 674816 B (16B aligned)
#define P2T_BYTES  ((size_t)NB*N2S*CC*4)        // 4 MiB

__device__ __forceinline__ float lrelu(float v){ return v > 0.f ? v : 0.1f*v; }
__device__ __forceinline__ float sigm(float v){ return 1.f/(1.f + __expf(-v)); }
__device__ __forceinline__ float tanh_(float v){ return 1.f - 2.f/(__expf(2.f*v) + 1.f); }

// ---------------- weight transpose: wT[c][o] = w[o][c], K padded to 68 with zeros ----------------
__global__ __launch_bounds__(256) void prep_weights(
    const float* __restrict__ r0, const float* __restrict__ z0, const float* __restrict__ h0,
    const float* __restrict__ r1, const float* __restrict__ z1, const float* __restrict__ h1,
    const float* __restrict__ fr, const float* __restrict__ fz, const float* __restrict__ fro,
    float* __restrict__ wt) {
  const float* srcs[9] = {r0, z0, h0, r1, z1, h1, fr, fz, fro};
  const int    kins[9] = {67, 67, 67, 64, 64, 64, 64, 64, 64};
  const int    offs[9] = {WT_R0_OFF, WT_Z0_OFF, WT_H0_OFF, WT_R1_OFF, WT_Z1_OFF,
                          WT_H1_OFF, WT_FR_OFF, WT_FZ_OFF, WT_FRO_OFF};
  const int m = blockIdx.x;
  const float* __restrict__ src = srcs[m];
  float* __restrict__ dst = wt + offs[m];
  const int kin = kins[m];
  const int nd = (kin == 67) ? 68*64 : 64*64;
  for (int d = threadIdx.x; d < nd; d += 256) {
    const int c = d >> 6, o = d & 63;
    dst[d] = (c < kin) ? src[o*kin + c] : 0.f;
  }
}

// ---------------- points2 transpose: [B,C,N2] -> [B,N2,C] ----------------
__global__ __launch_bounds__(256) void transpose_p2(const float* __restrict__ src, float* __restrict__ dst){
  __shared__ float t[64][65];
  const int b = blockIdx.y; const int j0 = blockIdx.x*64;
  const int tx = threadIdx.x & 63; const int r4 = threadIdx.x >> 6;
  #pragma unroll
  for (int c = r4; c < 64; c += 4) t[c][tx] = src[((size_t)b*CC + c)*N2S + j0 + tx];
  __syncthreads();
  #pragma unroll
  for (int j = r4; j < 64; j += 4) dst[((size_t)b*N2S + j0 + j)*CC + tx] = t[tx][j];
}

// ---------------- KNN: wave per query, ballot + serial shfl-insert ----------------
__global__ __launch_bounds__(256) void knn_kernel(
    const float* __restrict__ xyz1, const float* __restrict__ xyz2, int* __restrict__ idxout)
{
  __shared__ float4 T[KTILE];                 // (x,y,z,|p|^2) 16 KB
  const int tid = threadIdx.x;
  const int w = tid >> 6, lane = tid & 63;
  const int q = blockIdx.x*QPB + w;
  const int b = q >> 12, n = q & (N1S-1);
  const float* __restrict__ X2 = xyz2 + (size_t)b*3*N2S;
  const float qx = xyz1[((size_t)b*3+0)*N1S + n];
  const float qy = xyz1[((size_t)b*3+1)*N1S + n];
  const float qz = xyz1[((size_t)b*3+2)*N1S + n];
  const float s1 = (qx*qx + qy*qy) + qz*qz;

  float listd = INFINITY; int listi = 0; float kth = INFINITY;
  for (int t0 = 0; t0 < N2S; t0 += KTILE) {
    __syncthreads();
    for (int i = tid; i < KTILE; i += 256) {
      float x = X2[t0+i], y = X2[N2S+t0+i], z = X2[2*N2S+t0+i];
      T[i] = make_float4(x, y, z, (x*x + y*y) + z*z);
    }
    __syncthreads();
    for (int c0 = 0; c0 < KTILE; c0 += 64) {
      const float4 v = T[c0 + lane];
      // match reference formula: (|x1|^2 + |x2|^2) - 2*dot
      const float d = (s1 + v.w) - 2.f*((qx*v.x + qy*v.y) + qz*v.z);
      unsigned long long vote = __ballot(d < kth);
      while (vote) {
        const int src = (int)__builtin_ctzll(vote);
        vote &= vote - 1;
        const float dv = __shfl(d, src);
        if (dv < kth) {                        // uniform branch
          const int iv = t0 + c0 + src;
          const float ud = __shfl_up(listd, 1);
          const int   ui = __shfl_up(listi, 1);
          const bool cm = dv < listd;          // sorted ascending, strict < keeps lower index on ties
          const bool cp = (lane > 0) && (dv < ud);
          listd = cm ? (cp ? ud : dv) : listd;
          listi = cm ? (cp ? ui : iv) : listi;
          kth = __shfl(listd, KK-1);
        }
      }
    }
  }
  if (lane < KK) idxout[q*KK + lane] = listi;
}

// ---------------- gather + gates: wave per query, lane = out channel ----------------
__global__ __launch_bounds__(256) void gates_kernel(
    const float* __restrict__ xyz1, const float* __restrict__ xyz2,
    const float* __restrict__ points1, const float* __restrict__ p2g,
    const int sJ, const int sC, const int* __restrict__ knnidx,
    const float* __restrict__ wt,
    const float* __restrict__ b_r0, const float* __restrict__ b_r1,
    const float* __restrict__ b_z0, const float* __restrict__ b_z1,
    const float* __restrict__ b_h0, const float* __restrict__ b_h1,
    float* __restrict__ out)
{
  __shared__ float feat[QPB][KK][68];   // rows 272B (16B-aligned)
  __shared__ float bufA[QPB][KK][CC];   // r0 activations, then r*p1
  __shared__ float p1s[QPB][CC];
  __shared__ float vbuf[QPB][CC];
  __shared__ float obuf[CC][QPB];
  const int tid = threadIdx.x;
  const int w = tid >> 6, lane = tid & 63;
  const int q = blockIdx.x*QPB + w;
  const int b = q >> 12, n = q & (N1S-1);
  const float* __restrict__ X2 = xyz2 + (size_t)b*3*N2S;
  const float p1o = points1[((size_t)b*CC + lane)*N1S + n];
  p1s[w][lane] = p1o;

  // gather (wave-private LDS rows -> no cross-wave barriers needed)
  {
    const float* __restrict__ P2 = p2g + (size_t)b*CC*N2S;
    for (int k = 0; k < KK; k++) {
      const int j = knnidx[q*KK + k];
      feat[w][k][lane] = P2[(size_t)j*sJ + (size_t)lane*sC];
      if (lane < 3)
        feat[w][k][CC + lane] = X2[(size_t)lane*N2S + j] - xyz1[((size_t)b*3+lane)*N1S + n];
      if (lane == 3) feat[w][k][67] = 0.f;
    }
  }

  // fuse terms fr/fz from p1 (weights transposed: wT[c*64 + o], lane-coalesced)
  float frv = 0.f, fzv = 0.f;
  {
    const float* __restrict__ wfr = wt + WT_FR_OFF;
    const float* __restrict__ wfz = wt + WT_FZ_OFF;
    for (int c0 = 0; c0 < CC; c0 += 4) {
      const float4 p = *(const float4*)&p1s[w][c0];
      frv += wfr[(c0+0)*CC+lane]*p.x + wfr[(c0+1)*CC+lane]*p.y
           + wfr[(c0+2)*CC+lane]*p.z + wfr[(c0+3)*CC+lane]*p.w;
      fzv += wfz[(c0+0)*CC+lane]*p.x + wfz[(c0+1)*CC+lane]*p.y
           + wfz[(c0+2)*CC+lane]*p.z + wfz[(c0+3)*CC+lane]*p.w;
    }
  }

  // fused layer-0: r0/z0/h0 share feat reads (1 b128 read -> 12 FMA)
  float racc[KK], zacc[KK], hacc[KK];
  #pragma unroll
  for (int k = 0; k < KK; k++) { racc[k] = 0.f; zacc[k] = 0.f; hacc[k] = 0.f; }
  {
    const float* __restrict__ wr = wt + WT_R0_OFF;
    const float* __restrict__ wz = wt + WT_Z0_OFF;
    const float* __restrict__ wh = wt + WT_H0_OFF;
    for (int c0 = 0; c0 < 68; c0 += 4) {
      float wr4[4], wz4[4], wh4[4];
      #pragma unroll
      for (int i = 0; i < 4; i++) {
        wr4[i] = wr[(c0+i)*CC + lane];
        wz4[i] = wz[(c0+i)*CC + lane];
        wh4[i] = wh[(c0+i)*CC + lane];
      }
      #pragma unroll
      for (int k = 0; k < KK; k++) {
        const float4 f = *(const float4*)&feat[w][k][c0];
        racc[k] += wr4[0]*f.x + wr4[1]*f.y + wr4[2]*f.z + wr4[3]*f.w;
        zacc[k] += wz4[0]*f.x + wz4[1]*f.y + wz4[2]*f.z + wz4[3]*f.w;
        hacc[k] += wh4[0]*f.x + wh4[1]*f.y + wh4[2]*f.z + wh4[3]*f.w;
      }
    }
  }

  // r0 -> LDS, z-max -> vbuf
  const float br = b_r0[lane] + frv, bz = b_z0[lane] + fzv, bh = b_h0[lane];
  float zm = -INFINITY;
  #pragma unroll
  for (int k = 0; k < KK; k++) {
    bufA[w][k][lane] = lrelu(br + racc[k]);
    zm = fmaxf(zm, lrelu(bz + zacc[k]));
  }
  vbuf[w][lane] = zm;

  // z1 (reads all lanes' zm; wave-lockstep, in program order)
  float zg;
  {
    const float* __restrict__ wz1 = wt + WT_Z1_OFF;
    float za = 0.f;
    for (int c0 = 0; c0 < CC; c0 += 4) {
      const float4 vv = *(const float4*)&vbuf[w][c0];
      za += wz1[(c0+0)*CC+lane]*vv.x + wz1[(c0+1)*CC+lane]*vv.y
          + wz1[(c0+2)*CC+lane]*vv.z + wz1[(c0+3)*CC+lane]*vv.w;
    }
    zg = sigm(b_z1[lane] + za);
  }

  // r1: all reads of bufA (r0) happen before the r*p1 overwrite below
  float acc2[KK];
  #pragma unroll
  for (int k = 0; k < KK; k++) acc2[k] = 0.f;
  {
    const float* __restrict__ wr1 = wt + WT_R1_OFF;
    for (int c0 = 0; c0 < CC; c0 += 4) {
      float w4[4];
      #pragma unroll
      for (int i = 0; i < 4; i++) w4[i] = wr1[(c0+i)*CC + lane];
      #pragma unroll
      for (int k = 0; k < KK; k++) {
        const float4 f = *(const float4*)&bufA[w][k][c0];
        acc2[k] += w4[0]*f.x + w4[1]*f.y + w4[2]*f.z + w4[3]*f.w;
      }
    }
  }
  {
    const float br1 = b_r1[lane];
    #pragma unroll
    for (int k = 0; k < KK; k++)
      bufA[w][k][lane] = sigm(br1 + acc2[k]) * p1o;   // r*p1
  }

  // fro on (r*p1) -> p1e[k] (reuse acc2)
  #pragma unroll
  for (int k = 0; k < KK; k++) acc2[k] = 0.f;
  {
    const float* __restrict__ wro = wt + WT_FRO_OFF;
    for (int c0 = 0; c0 < CC; c0 += 4) {
      float w4[4];
      #pragma unroll
      for (int i = 0; i < 4; i++) w4[i] = wro[(c0+i)*CC + lane];
      #pragma unroll
      for (int k = 0; k < KK; k++) {
        const float4 f = *(const float4*)&bufA[w][k][c0];
        acc2[k] += w4[0]*f.x + w4[1]*f.y + w4[2]*f.z + w4[3]*f.w;
      }
    }
  }

  // h-max -> vbuf (z1 reads already done in program order), h1
  float hm = -INFINITY;
  #pragma unroll
  for (int k = 0; k < KK; k++) hm = fmaxf(hm, lrelu(bh + hacc[k] + acc2[k]));
  vbuf[w][lane] = hm;
  float hg;
  {
    const float* __restrict__ wh1 = wt + WT_H1_OFF;
    float ha = 0.f;
    for (int c0 = 0; c0 < CC; c0 += 4) {
      const float4 vv = *(const float4*)&vbuf[w][c0];
      ha += wh1[(c0+0)*CC+lane]*vv.x + wh1[(c0+1)*CC+lane]*vv.y
          + wh1[(c0+2)*CC+lane]*vv.z + wh1[(c0+3)*CC+lane]*vv.w;
    }
    hg = tanh_(b_h1[lane] + ha);
  }

  obuf[lane][w] = (1.f - zg)*p1o + zg*hg;
  __syncthreads();
  // 16B-grouped store: thread t writes channel t>>2, point offset t&3
  {
    const int c = tid >> 2, nn = tid & 3;
    const int q0 = blockIdx.x*QPB;
    const int b0 = q0 >> 12, n0 = q0 & (N1S-1);
    out[((size_t)b0*CC + c)*N1S + n0 + nn] = obuf[c][nn];
  }
}

extern "C" void kernel_launch(void* const* d_in, const int* in_sizes, int n_in,
                              void* d_out, int out_size, void* d_ws, size_t ws_size,
                              hipStream_t stream) {
  const float* xyz1    = (const float*)d_in[0];
  const float* xyz2    = (const float*)d_in[1];
  const float* points1 = (const float*)d_in[2];
  const float* points2 = (const float*)d_in[3];
  const float* w_r0 = (const float*)d_in[4];
  const float* b_r0 = (const float*)d_in[5];
  const float* w_r1 = (const float*)d_in[6];
  const float* b_r1 = (const float*)d_in[7];
  const float* w_z0 = (const float*)d_in[8];
  const float* b_z0 = (const float*)d_in[9];
  const float* w_z1 = (const float*)d_in[10];
  const float* b_z1 = (const float*)d_in[11];
  const float* w_h0 = (const float*)d_in[12];
  const float* b_h0 = (const float*)d_in[13];
  const float* w_h1 = (const float*)d_in[14];
  const float* b_h1 = (const float*)d_in[15];
  const float* w_fr  = (const float*)d_in[16];
  const float* w_fz  = (const float*)d_in[17];
  const float* w_fro = (const float*)d_in[18];
  float* out = (float*)d_out;

  float* wt   = (float*)d_ws;
  int*   kidx = (int*)((char*)d_ws + IDX_OFF_B);
  float* p2t  = (float*)((char*)d_ws + P2T_OFF_B);

  prep_weights<<<9, 256, 0, stream>>>(w_r0, w_z0, w_h0, w_r1, w_z1, w_h1,
                                      w_fr, w_fz, w_fro, wt);

  const bool useT = (ws_size >= (size_t)P2T_OFF_B + P2T_BYTES);
  const float* p2g = points2; int sJ = 1, sC = N2S;
  if (useT) {
    transpose_p2<<<dim3(N2S/64, NB), dim3(256), 0, stream>>>(points2, p2t);
    p2g = p2t; sJ = CC; sC = 1;
  }

  knn_kernel<<<dim3(NB*N1S/QPB), dim3(256), 0, stream>>>(xyz1, xyz2, kidx);

  gates_kernel<<<dim3(NB*N1S/QPB), dim3(256), 0, stream>>>(
      xyz1, xyz2, points1, p2g, sJ, sC, kidx, wt,
      b_r0, b_r1, b_z0, b_z1, b_h0, b_h1, out);
}

// Round 3
// 211.180 us; speedup vs baseline: 4.1911x; 2.5552x over previous
//
#include <hip/hip_runtime.h>
#include <math.h>

typedef __attribute__((ext_vector_type(8))) short bf8_t;
typedef __attribute__((ext_vector_type(4))) float f32x4;

#define NB   2
#define N1S  4096
#define N2S  8192
#define CC   64
#define KK   16
#define GQ   8

// mat ids in wA
#define M_R0 0
#define M_Z0 1
#define M_H0 2
#define M_R1 3
#define M_Z1 4
#define M_H1 5
#define M_FR 6
#define M_FZ 7
#define M_FRO 8

// ---- ws layout (bytes) ----
#define WA_SHORTS   (9*4*2*64*8)                 // 36864 shorts = 73728 B
#define WDIR_OFF    (WA_SHORTS*2)                // 73728
#define WDIR_FLOATS (3*3*64)                     // 576
#define XP_OFF      (WDIR_OFF + WDIR_FLOATS*4)   // 76032 (16B aligned)
#define XP_BYTES    (NB*N2S*16)                  // 262144
#define KIDX_OFF    (XP_OFF + XP_BYTES)          // 338176
#define KIDX_BYTES  (NB*N1S*KK*4)                // 524288
#define P2T_OFF     (KIDX_OFF + KIDX_BYTES)      // 862464 (16B aligned)
#define P2T_BYTES   ((size_t)NB*N2S*CC*4)        // 4 MiB

__device__ __forceinline__ float lrelu(float v){ return v > 0.f ? v : 0.1f*v; }
__device__ __forceinline__ float sigm(float v){ return 1.f/(1.f + __expf(-v)); }
__device__ __forceinline__ float tanh_(float v){ return 1.f - 2.f/(__expf(2.f*v) + 1.f); }
__device__ __forceinline__ unsigned short f2bf(float f){
  union { float f; unsigned u; } v; v.f = f;
  unsigned r = v.u + 0x7FFF + ((v.u >> 16) & 1);
  return (unsigned short)(r >> 16);
}

// ---------------- prep: pack 9 weight matrices into A-fragment layout + dir weights ----------------
__global__ __launch_bounds__(256) void prep_wA(
    const float* __restrict__ r0, const float* __restrict__ z0, const float* __restrict__ h0,
    const float* __restrict__ r1, const float* __restrict__ z1, const float* __restrict__ h1,
    const float* __restrict__ fr, const float* __restrict__ fz, const float* __restrict__ fro,
    short* __restrict__ wa, float* __restrict__ wdir)
{
  const float* W[9] = {r0, z0, h0, r1, z1, h1, fr, fz, fro};
  const int Ks[9]   = {67, 67, 67, 64, 64, 64, 64, 64, 64};
  const int stride = gridDim.x * 256;
  for (int i = blockIdx.x*256 + threadIdx.x; i < WA_SHORTS; i += stride) {
    const int j = i & 7, l = (i >> 3) & 63, kk = (i >> 9) & 1, r = (i >> 10) & 3, mat = i >> 12;
    const int row = r*16 + (l & 15);
    const int c = kk*32 + ((l >> 4) << 3) + j;
    wa[i] = (short)f2bf(W[mat][row*Ks[mat] + c]);
  }
  for (int i = blockIdx.x*256 + threadIdx.x; i < WDIR_FLOATS; i += stride) {
    const int g = i / 192, rem = i % 192, d = rem / 64, o = rem & 63;
    wdir[i] = W[g][o*67 + 64 + d];
  }
}

// ---------------- pack xyz2 as float4(x,y,z,|p|^2) ----------------
__global__ __launch_bounds__(256) void pack_xyz2(const float* __restrict__ xyz2, float4* __restrict__ xp){
  const int i = blockIdx.x*256 + threadIdx.x;     // 0 .. 16383
  const int b = i >> 13, j = i & (N2S-1);
  const float x = xyz2[((size_t)(b*3+0))*N2S + j];
  const float y = xyz2[((size_t)(b*3+1))*N2S + j];
  const float z = xyz2[((size_t)(b*3+2))*N2S + j];
  xp[i] = make_float4(x, y, z, (x*x + y*y) + z*z);
}

// ---------------- points2 transpose: [B,C,N2] -> [B,N2,C] ----------------
__global__ __launch_bounds__(256) void transpose_p2(const float* __restrict__ src, float* __restrict__ dst){
  __shared__ float t[64][65];
  const int b = blockIdx.y; const int j0 = blockIdx.x*64;
  const int tx = threadIdx.x & 63; const int r4 = threadIdx.x >> 6;
  #pragma unroll
  for (int c = r4; c < 64; c += 4) t[c][tx] = src[((size_t)b*CC + c)*N2S + j0 + tx];
  __syncthreads();
  #pragma unroll
  for (int j = r4; j < 64; j += 4) dst[((size_t)b*N2S + j0 + j)*CC + tx] = t[tx][j];
}

// ---------------- KNN: 2 queries per wave, candidates streamed from L2 ----------------
__global__ __launch_bounds__(256) void knn_kernel(
    const float* __restrict__ xyz1, const float4* __restrict__ xp, int* __restrict__ idxout)
{
  const int tid = threadIdx.x, w = tid >> 6, lane = tid & 63, grp = lane >> 4;
  const int qbase = blockIdx.x*8 + w*2;            // even; pair never crosses batch boundary
  const int b = qbase >> 12;
  const float4* __restrict__ X = xp + (b << 13);
  float qx[2], qy[2], qz[2], s1[2], kth[2];
  #pragma unroll
  for (int g = 0; g < 2; g++) {
    const int n = (qbase + g) & (N1S-1);
    qx[g] = xyz1[((size_t)(b*3+0))*N1S + n];
    qy[g] = xyz1[((size_t)(b*3+1))*N1S + n];
    qz[g] = xyz1[((size_t)(b*3+2))*N1S + n];
    s1[g] = (qx[g]*qx[g] + qy[g]*qy[g]) + qz[g]*qz[g];
    kth[g] = INFINITY;
  }
  float listd = INFINITY; int listi = 0;
  for (int c0 = 0; c0 < N2S; c0 += 128) {
    const float4 v0 = X[c0 + lane];
    const float4 v1 = X[c0 + 64 + lane];
    #pragma unroll
    for (int h = 0; h < 2; h++) {
      const float4 v = h ? v1 : v0;
      const int base = c0 + h*64;
      #pragma unroll
      for (int g = 0; g < 2; g++) {
        // EXACT same distance expression as r2 (keeps neighbor sets identical)
        const float d = (s1[g] + v.w) - 2.f*((qx[g]*v.x + qy[g]*v.y) + qz[g]*v.z);
        unsigned long long vote = __ballot(d < kth[g]);
        while (vote) {
          const int src = (int)__builtin_ctzll(vote);
          vote &= vote - 1;
          const float dv = __shfl(d, src);
          if (dv < kth[g]) {                      // uniform
            const int iv = base + src;
            const float ud = __shfl_up(listd, 1);
            const int   ui = __shfl_up(listi, 1);
            const bool ing = (grp == g);
            const bool cm = ing && (dv < listd);
            const bool cp = cm && ((lane & 15) > 0) && (dv < ud);
            listd = cm ? (cp ? ud : dv) : listd;
            listi = cm ? (cp ? ui : iv) : listi;
            kth[g] = __shfl(listd, g*16 + 15);
          }
        }
      }
    }
  }
  if (grp < 2) idxout[(size_t)(qbase + grp)*KK + (lane & 15)] = listi;
}

// ---------------- gates: MFMA pipeline, 8 queries / block, 4 waves = 4 row-tiles ----------------
#define FRAG(mat, kk) (*(const bf8_t*)(wA + (((mat)*4 + w)*2 + (kk))*512 + lane*8))

__global__ __launch_bounds__(256) void gates_kernel(
    const float* __restrict__ xyz1, const float* __restrict__ xyz2,
    const float* __restrict__ points1, const float* __restrict__ p2t,
    const int* __restrict__ kidx, const short* __restrict__ wA,
    const float* __restrict__ wdir,
    const float* __restrict__ b_r0, const float* __restrict__ b_z0,
    const float* __restrict__ b_h0, const float* __restrict__ b_r1,
    const float* __restrict__ b_z1, const float* __restrict__ b_h1,
    float* __restrict__ out)
{
  __shared__ __align__(16) short featB[2][GQ][64][8];  // p2 channels, B-frag packed (16 KB)
  __shared__ __align__(16) short rB[2][GQ][64][8];     // r0 acts, then r*p1 in-place (16 KB)
  __shared__ __align__(16) float p1f[64][GQ];
  __shared__ __align__(16) short p1B[2][64][8];
  __shared__ float BFr[64][GQ], BFz[64][GQ];
  __shared__ float zmaxL[64][GQ], hmaxL[64][GQ];
  __shared__ float biasL[6][64];
  __shared__ float dirL[3][GQ*KK];
  __shared__ __align__(16) float obuf[64][GQ];

  const int tid = threadIdx.x;
  const int w = tid >> 6, lane = tid & 63;
  const int b  = blockIdx.x >> 9;
  const int n0 = (blockIdx.x & 511) * GQ;
  const int cq = lane & 15;                       // C col within tile (= query q)
  const int reg_o0 = w*16 + ((lane >> 4) << 2);   // first of this lane's 4 C rows
  const f32x4 zero4 = {0.f, 0.f, 0.f, 0.f};

  // ---- P0a ----
  for (int i = tid; i < 6*64; i += 256) {
    const int a = i >> 6, o = i & 63;
    const float* bp = (a==0)?b_r0:(a==1)?b_z0:(a==2)?b_h0:(a==3)?b_r1:(a==4)?b_z1:b_h1;
    biasL[a][o] = bp[o];
  }
  if (tid < 64) {
    const float* sp = points1 + ((size_t)(b*CC + tid))*N1S + n0;
    *(float4*)&p1f[tid][0] = ((const float4*)sp)[0];
    *(float4*)&p1f[tid][4] = ((const float4*)sp)[1];
  }
  ((unsigned long long*)&p1B[0][0][0])[tid] = 0ULL;   // zero 2048 B
  if (tid < 128) {                                    // dir channels
    const int m = tid, qg = n0 + (m >> 4);
    const int j = kidx[(size_t)((b << 12) + qg)*KK + (m & 15)];
    #pragma unroll
    for (int d = 0; d < 3; d++)
      dirL[d][m] = xyz2[((size_t)(b*3+d))*N2S + j] - xyz1[((size_t)(b*3+d))*N1S + qg];
  }
  {                                                   // p2 feature gather -> featB (B-frag packed)
    const int m = tid >> 1, half = tid & 1;
    const int qg = n0 + (m >> 4);
    const int j = kidx[(size_t)((b << 12) + qg)*KK + (m & 15)];
    const float* __restrict__ src = p2t + ((size_t)(b << 13) + j)*CC + half*32;
    float v[32];
    #pragma unroll
    for (int i = 0; i < 8; i++) {
      const float4 f = ((const float4*)src)[i];
      v[i*4] = f.x; v[i*4+1] = f.y; v[i*4+2] = f.z; v[i*4+3] = f.w;
    }
    #pragma unroll
    for (int gi = 0; gi < 4; gi++) {
      bf8_t pk;
      #pragma unroll
      for (int j2 = 0; j2 < 8; j2++) pk[j2] = (short)f2bf(v[gi*8 + j2]);
      *(bf8_t*)&featB[half][m >> 4][gi*16 + (m & 15)][0] = pk;
    }
  }
  __syncthreads();

  // ---- P0b: p1 as B-frag (cols 0..7 valid, rest zero) ----
  {
    const int s0 = tid*4;
    const int j0 = s0 & 7, l = (s0 >> 3) & 63, kk = s0 >> 9;
    const int q = l & 15;
    if (q < 8) {
      unsigned short t0[4];
      #pragma unroll
      for (int jj = 0; jj < 4; jj++)
        t0[jj] = f2bf(p1f[kk*32 + ((l >> 4) << 3) + j0 + jj][q]);
      uint2 pk; pk.x = t0[0] | ((unsigned)t0[1] << 16); pk.y = t0[2] | ((unsigned)t0[3] << 16);
      *(uint2*)&p1B[kk][l][j0] = pk;
    }
  }
  __syncthreads();

  // ---- P1: fuse GEMMs -> BFr/BFz (wave-private rows, no barrier needed after) ----
  {
    const bf8_t fa0 = FRAG(M_FR, 0), fa1 = FRAG(M_FR, 1);
    const bf8_t ga0 = FRAG(M_FZ, 0), ga1 = FRAG(M_FZ, 1);
    const bf8_t pb0 = *(const bf8_t*)&p1B[0][lane][0];
    const bf8_t pb1 = *(const bf8_t*)&p1B[1][lane][0];
    f32x4 ar = __builtin_amdgcn_mfma_f32_16x16x32_bf16(fa0, pb0, zero4, 0, 0, 0);
    ar = __builtin_amdgcn_mfma_f32_16x16x32_bf16(fa1, pb1, ar, 0, 0, 0);
    f32x4 az = __builtin_amdgcn_mfma_f32_16x16x32_bf16(ga0, pb0, zero4, 0, 0, 0);
    az = __builtin_amdgcn_mfma_f32_16x16x32_bf16(ga1, pb1, az, 0, 0, 0);
    if (cq < 8) {
      #pragma unroll
      for (int r2 = 0; r2 < 4; r2++) {
        const int o = reg_o0 + r2;
        BFr[o][cq] = ar[r2] + biasL[0][o];
        BFz[o][cq] = az[r2] + biasL[1][o];
      }
    }
  }

  // ---- P1b: layer-0 r/z (+dir epilogue), write r0 B-frags, z max-reduce ----
  {
    const bf8_t ra0 = FRAG(M_R0, 0), ra1 = FRAG(M_R0, 1);
    const bf8_t za0 = FRAG(M_Z0, 0), za1 = FRAG(M_Z0, 1);
    float wdr[3][4], wdz[3][4];
    #pragma unroll
    for (int d = 0; d < 3; d++)
      #pragma unroll
      for (int r2 = 0; r2 < 4; r2++) {
        wdr[d][r2] = wdir[(0*3 + d)*64 + reg_o0 + r2];
        wdz[d][r2] = wdir[(1*3 + d)*64 + reg_o0 + r2];
      }
    const int kkv = reg_o0 >> 5, lp = ((reg_o0 & 31) >> 3)*16 + cq, j0 = reg_o0 & 7;
    #pragma unroll
    for (int ct = 0; ct < GQ; ct++) {
      const bf8_t fb0 = *(const bf8_t*)&featB[0][ct][lane][0];
      const bf8_t fb1 = *(const bf8_t*)&featB[1][ct][lane][0];
      f32x4 accr = __builtin_amdgcn_mfma_f32_16x16x32_bf16(ra0, fb0, zero4, 0, 0, 0);
      accr = __builtin_amdgcn_mfma_f32_16x16x32_bf16(ra1, fb1, accr, 0, 0, 0);
      f32x4 accz = __builtin_amdgcn_mfma_f32_16x16x32_bf16(za0, fb0, zero4, 0, 0, 0);
      accz = __builtin_amdgcn_mfma_f32_16x16x32_bf16(za1, fb1, accz, 0, 0, 0);
      const int m = ct*16 + cq;
      const float d0 = dirL[0][m], d1 = dirL[1][m], d2 = dirL[2][m];
      unsigned short rpk[4]; float zv[4];
      #pragma unroll
      for (int r2 = 0; r2 < 4; r2++) {
        const int o = reg_o0 + r2;
        float rv = accr[r2] + BFr[o][ct] + wdr[0][r2]*d0 + wdr[1][r2]*d1 + wdr[2][r2]*d2;
        rpk[r2] = f2bf(lrelu(rv));
        float zt = accz[r2] + BFz[o][ct] + wdz[0][r2]*d0 + wdz[1][r2]*d1 + wdz[2][r2]*d2;
        zv[r2] = lrelu(zt);
      }
      uint2 pk; pk.x = rpk[0] | ((unsigned)rpk[1] << 16); pk.y = rpk[2] | ((unsigned)rpk[3] << 16);
      *(uint2*)&rB[kkv][ct][lp][j0] = pk;
      #pragma unroll
      for (int r2 = 0; r2 < 4; r2++) {
        float vv = zv[r2];
        vv = fmaxf(vv, __shfl_xor(vv, 1));
        vv = fmaxf(vv, __shfl_xor(vv, 2));
        vv = fmaxf(vv, __shfl_xor(vv, 4));
        vv = fmaxf(vv, __shfl_xor(vv, 8));
        zv[r2] = vv;
      }
      if (cq == 0) {
        #pragma unroll
        for (int r2 = 0; r2 < 4; r2++) zmaxL[reg_o0 + r2][ct] = zv[r2];
      }
    }
  }
  __syncthreads();

  // ---- P2: r1 (hold r*p1 packed in regs), z1 ----
  uint2 rpK[GQ];
  float zg[4];
  {
    const bf8_t r1a0 = FRAG(M_R1, 0), r1a1 = FRAG(M_R1, 1);
    #pragma unroll
    for (int ct = 0; ct < GQ; ct++) {
      const bf8_t b0 = *(const bf8_t*)&rB[0][ct][lane][0];
      const bf8_t b1 = *(const bf8_t*)&rB[1][ct][lane][0];
      f32x4 acc = __builtin_amdgcn_mfma_f32_16x16x32_bf16(r1a0, b0, zero4, 0, 0, 0);
      acc = __builtin_amdgcn_mfma_f32_16x16x32_bf16(r1a1, b1, acc, 0, 0, 0);
      unsigned short pk4[4];
      #pragma unroll
      for (int r2 = 0; r2 < 4; r2++) {
        const int o = reg_o0 + r2;
        const float rg = sigm(acc[r2] + biasL[3][o]);
        pk4[r2] = f2bf(rg * p1f[o][ct]);
      }
      rpK[ct].x = pk4[0] | ((unsigned)pk4[1] << 16);
      rpK[ct].y = pk4[2] | ((unsigned)pk4[3] << 16);
    }
    const bf8_t z1a0 = FRAG(M_Z1, 0), z1a1 = FRAG(M_Z1, 1);
    const int qc = cq < 8 ? cq : 7;
    bf8_t zb0, zb1;
    #pragma unroll
    for (int j = 0; j < 8; j++) {
      zb0[j] = (short)f2bf(zmaxL[((lane >> 4) << 3) + j][qc]);
      zb1[j] = (short)f2bf(zmaxL[32 + ((lane >> 4) << 3) + j][qc]);
    }
    f32x4 az = __builtin_amdgcn_mfma_f32_16x16x32_bf16(z1a0, zb0, zero4, 0, 0, 0);
    az = __builtin_amdgcn_mfma_f32_16x16x32_bf16(z1a1, zb1, az, 0, 0, 0);
    #pragma unroll
    for (int r2 = 0; r2 < 4; r2++) zg[r2] = sigm(az[r2] + biasL[4][reg_o0 + r2]);
  }
  __syncthreads();

  // ---- P2b: overwrite rB with r*p1 ----
  {
    const int kkv = reg_o0 >> 5, lp = ((reg_o0 & 31) >> 3)*16 + cq, j0 = reg_o0 & 7;
    #pragma unroll
    for (int ct = 0; ct < GQ; ct++) *(uint2*)&rB[kkv][ct][lp][j0] = rpK[ct];
  }
  __syncthreads();

  // ---- P3: h0·feat + fro·(r*p1) (+dir), h max-reduce ----
  {
    const bf8_t h0a0 = FRAG(M_H0, 0), h0a1 = FRAG(M_H0, 1);
    const bf8_t foa0 = FRAG(M_FRO, 0), foa1 = FRAG(M_FRO, 1);
    float wdh[3][4];
    #pragma unroll
    for (int d = 0; d < 3; d++)
      #pragma unroll
      for (int r2 = 0; r2 < 4; r2++) wdh[d][r2] = wdir[(2*3 + d)*64 + reg_o0 + r2];
    #pragma unroll
    for (int ct = 0; ct < GQ; ct++) {
      const bf8_t fb0 = *(const bf8_t*)&featB[0][ct][lane][0];
      const bf8_t fb1 = *(const bf8_t*)&featB[1][ct][lane][0];
      const bf8_t rb0 = *(const bf8_t*)&rB[0][ct][lane][0];
      const bf8_t rb1 = *(const bf8_t*)&rB[1][ct][lane][0];
      f32x4 acc = __builtin_amdgcn_mfma_f32_16x16x32_bf16(h0a0, fb0, zero4, 0, 0, 0);
      acc = __builtin_amdgcn_mfma_f32_16x16x32_bf16(h0a1, fb1, acc, 0, 0, 0);
      acc = __builtin_amdgcn_mfma_f32_16x16x32_bf16(foa0, rb0, acc, 0, 0, 0);
      acc = __builtin_amdgcn_mfma_f32_16x16x32_bf16(foa1, rb1, acc, 0, 0, 0);
      const int m = ct*16 + cq;
      const float d0 = dirL[0][m], d1 = dirL[1][m], d2 = dirL[2][m];
      float hv[4];
      #pragma unroll
      for (int r2 = 0; r2 < 4; r2++) {
        const int o = reg_o0 + r2;
        hv[r2] = lrelu(acc[r2] + biasL[2][o] + wdh[0][r2]*d0 + wdh[1][r2]*d1 + wdh[2][r2]*d2);
      }
      #pragma unroll
      for (int r2 = 0; r2 < 4; r2++) {
        float vv = hv[r2];
        vv = fmaxf(vv, __shfl_xor(vv, 1));
        vv = fmaxf(vv, __shfl_xor(vv, 2));
        vv = fmaxf(vv, __shfl_xor(vv, 4));
        vv = fmaxf(vv, __shfl_xor(vv, 8));
        hv[r2] = vv;
      }
      if (cq == 0) {
        #pragma unroll
        for (int r2 = 0; r2 < 4; r2++) hmaxL[reg_o0 + r2][ct] = hv[r2];
      }
    }
  }
  __syncthreads();

  // ---- P4: h1, final blend ----
  {
    const bf8_t h1a0 = FRAG(M_H1, 0), h1a1 = FRAG(M_H1, 1);
    const int qc = cq < 8 ? cq : 7;
    bf8_t hb0, hb1;
    #pragma unroll
    for (int j = 0; j < 8; j++) {
      hb0[j] = (short)f2bf(hmaxL[((lane >> 4) << 3) + j][qc]);
      hb1[j] = (short)f2bf(hmaxL[32 + ((lane >> 4) << 3) + j][qc]);
    }
    f32x4 ah = __builtin_amdgcn_mfma_f32_16x16x32_bf16(h1a0, hb0, zero4, 0, 0, 0);
    ah = __builtin_amdgcn_mfma_f32_16x16x32_bf16(h1a1, hb1, ah, 0, 0, 0);
    if (cq < 8) {
      #pragma unroll
      for (int r2 = 0; r2 < 4; r2++) {
        const int o = reg_o0 + r2;
        const float hg = tanh_(ah[r2] + biasL[5][o]);
        obuf[o][cq] = (1.f - zg[r2])*p1f[o][cq] + zg[r2]*hg;
      }
    }
  }
  __syncthreads();
  if (tid < 128) {
    const int c = tid >> 1, q4 = (tid & 1)*4;
    *(float4*)(out + ((size_t)(b*CC + c))*N1S + n0 + q4) = *(float4*)&obuf[c][q4];
  }
}

extern "C" void kernel_launch(void* const* d_in, const int* in_sizes, int n_in,
                              void* d_out, int out_size, void* d_ws, size_t ws_size,
                              hipStream_t stream) {
  const float* xyz1    = (const float*)d_in[0];
  const float* xyz2    = (const float*)d_in[1];
  const float* points1 = (const float*)d_in[2];
  const float* points2 = (const float*)d_in[3];
  const float* w_r0 = (const float*)d_in[4];
  const float* b_r0 = (const float*)d_in[5];
  const float* w_r1 = (const float*)d_in[6];
  const float* b_r1 = (const float*)d_in[7];
  const float* w_z0 = (const float*)d_in[8];
  const float* b_z0 = (const float*)d_in[9];
  const float* w_z1 = (const float*)d_in[10];
  const float* b_z1 = (const float*)d_in[11];
  const float* w_h0 = (const float*)d_in[12];
  const float* b_h0 = (const float*)d_in[13];
  const float* w_h1 = (const float*)d_in[14];
  const float* b_h1 = (const float*)d_in[15];
  const float* w_fr  = (const float*)d_in[16];
  const float* w_fz  = (const float*)d_in[17];
  const float* w_fro = (const float*)d_in[18];
  float* out = (float*)d_out;

  short*  wa   = (short*)d_ws;
  float*  wdir = (float*)((char*)d_ws + WDIR_OFF);
  float4* xp   = (float4*)((char*)d_ws + XP_OFF);
  int*    kidx = (int*)((char*)d_ws + KIDX_OFF);
  float*  p2t  = (float*)((char*)d_ws + P2T_OFF);

  prep_wA<<<16, 256, 0, stream>>>(w_r0, w_z0, w_h0, w_r1, w_z1, w_h1,
                                  w_fr, w_fz, w_fro, wa, wdir);
  pack_xyz2<<<64, 256, 0, stream>>>(xyz2, xp);
  transpose_p2<<<dim3(N2S/64, NB), dim3(256), 0, stream>>>(points2, p2t);

  knn_kernel<<<1024, 256, 0, stream>>>(xyz1, xp, kidx);

  gates_kernel<<<1024, 256, 0, stream>>>(
      xyz1, xyz2, points1, p2t, kidx, wa, wdir,
      b_r0, b_z0, b_h0, b_r1, b_z1, b_h1, out);
}

// Round 4
// 198.838 us; speedup vs baseline: 4.4512x; 1.0621x over previous
//
#include <hip/hip_runtime.h>
#include <math.h>

typedef __attribute__((ext_vector_type(8))) short bf8_t;
typedef __attribute__((ext_vector_type(4))) float f32x4;

#define NB   2
#define N1S  4096
#define N2S  8192
#define CC   64
#define KK   16
#define GQ   8
#define KTILE 2048

// mat ids in wA
#define M_R0 0
#define M_Z0 1
#define M_H0 2
#define M_R1 3
#define M_Z1 4
#define M_H1 5
#define M_FR 6
#define M_FZ 7
#define M_FRO 8

// ---- ws layout (bytes) ----
#define WA_SHORTS   (9*4*2*64*8)                 // 36864 shorts = 73728 B
#define WDIR_OFF    (WA_SHORTS*2)                // 73728
#define WDIR_FLOATS (3*3*64)                     // 576
#define XP_OFF      (WDIR_OFF + WDIR_FLOATS*4)   // 76032 (16B aligned)
#define XP_BYTES    (NB*N2S*16)                  // 262144
#define KIDX_OFF    (XP_OFF + XP_BYTES)          // 338176
#define KIDX_BYTES  (NB*N1S*KK*4)                // 524288
#define P2B_OFF     (KIDX_OFF + KIDX_BYTES)      // 862464 (16B aligned)
#define P2B_BYTES   ((size_t)NB*N2S*CC*2)        // 2 MiB (bf16)

__device__ __forceinline__ float lrelu(float v){ return v > 0.f ? v : 0.1f*v; }
__device__ __forceinline__ float sigm(float v){ return 1.f/(1.f + __expf(-v)); }
__device__ __forceinline__ float tanh_(float v){ return 1.f - 2.f/(__expf(2.f*v) + 1.f); }
__device__ __forceinline__ unsigned short f2bf(float f){
  union { float f; unsigned u; } v; v.f = f;
  unsigned r = v.u + 0x7FFF + ((v.u >> 16) & 1);
  return (unsigned short)(r >> 16);
}

// ---------------- prep: pack 9 weight matrices into A-fragment layout + dir weights ----------------
__global__ __launch_bounds__(256) void prep_wA(
    const float* __restrict__ r0, const float* __restrict__ z0, const float* __restrict__ h0,
    const float* __restrict__ r1, const float* __restrict__ z1, const float* __restrict__ h1,
    const float* __restrict__ fr, const float* __restrict__ fz, const float* __restrict__ fro,
    short* __restrict__ wa, float* __restrict__ wdir)
{
  const float* W[9] = {r0, z0, h0, r1, z1, h1, fr, fz, fro};
  const int Ks[9]   = {67, 67, 67, 64, 64, 64, 64, 64, 64};
  const int stride = gridDim.x * 256;
  for (int i = blockIdx.x*256 + threadIdx.x; i < WA_SHORTS; i += stride) {
    const int j = i & 7, l = (i >> 3) & 63, kk = (i >> 9) & 1, r = (i >> 10) & 3, mat = i >> 12;
    const int row = r*16 + (l & 15);
    const int c = kk*32 + ((l >> 4) << 3) + j;
    wa[i] = (short)f2bf(W[mat][row*Ks[mat] + c]);
  }
  for (int i = blockIdx.x*256 + threadIdx.x; i < WDIR_FLOATS; i += stride) {
    const int g = i / 192, rem = i % 192, d = rem / 64, o = rem & 63;
    wdir[i] = W[g][o*67 + 64 + d];
  }
}

// ---------------- pack xyz2 as float4(x,y,z,|p|^2) ----------------
__global__ __launch_bounds__(256) void pack_xyz2(const float* __restrict__ xyz2, float4* __restrict__ xp){
  const int i = blockIdx.x*256 + threadIdx.x;     // 0 .. 16383
  const int b = i >> 13, j = i & (N2S-1);
  const float x = xyz2[((size_t)(b*3+0))*N2S + j];
  const float y = xyz2[((size_t)(b*3+1))*N2S + j];
  const float z = xyz2[((size_t)(b*3+2))*N2S + j];
  xp[i] = make_float4(x, y, z, (x*x + y*y) + z*z);
}

// ---------------- points2 transpose + bf16: [B,C,N2] f32 -> [B,N2,C] bf16 ----------------
__global__ __launch_bounds__(256) void transpose_p2(const float* __restrict__ src, unsigned short* __restrict__ dst){
  __shared__ float t[64][65];
  const int b = blockIdx.y; const int j0 = blockIdx.x*64;
  const int tx = threadIdx.x & 63; const int r4 = threadIdx.x >> 6;
  #pragma unroll
  for (int c = r4; c < 64; c += 4) t[c][tx] = src[((size_t)b*CC + c)*N2S + j0 + tx];
  __syncthreads();
  #pragma unroll
  for (int j = r4; j < 64; j += 4) dst[((size_t)b*N2S + j0 + j)*CC + tx] = f2bf(t[tx][j]);
}

// ---------------- KNN: 4 queries/wave, two-pass (kappa prune) + exact streaming insert ----------------
__global__ __launch_bounds__(256) void knn_kernel(
    const float* __restrict__ xyz1, const float4* __restrict__ xp, int* __restrict__ idxout)
{
  __shared__ float4 T[KTILE];                      // 32 KB tile
  const int tid = threadIdx.x, w = tid >> 6, lane = tid & 63, grp = lane >> 4;
  const int qbase = blockIdx.x*16 + w*4;           // 16 queries/block; never crosses batch
  const int b = qbase >> 12;
  const float4* __restrict__ X = xp + (b << 13);
  float qx[4], qy[4], qz[4], s1[4], kth[4], kappa[4], m[4];
  #pragma unroll
  for (int g = 0; g < 4; g++) {
    const int n = (qbase + g) & (N1S-1);
    qx[g] = xyz1[((size_t)(b*3+0))*N1S + n];
    qy[g] = xyz1[((size_t)(b*3+1))*N1S + n];
    qz[g] = xyz1[((size_t)(b*3+2))*N1S + n];
    s1[g] = (qx[g]*qx[g] + qy[g]*qy[g]) + qz[g]*qz[g];
    kth[g] = INFINITY; m[g] = INFINITY;
  }

  // ---- pass 1: per-lane minima over lane's private partition (idx ≡ lane mod 64) ----
  for (int t0 = 0; t0 < N2S; t0 += KTILE) {
    __syncthreads();
    for (int i = tid; i < KTILE; i += 256) T[i] = X[t0 + i];
    __syncthreads();
    for (int c0 = 0; c0 < KTILE; c0 += 64) {
      const float4 v = T[c0 + lane];
      #pragma unroll
      for (int g = 0; g < 4; g++) {
        const float d = (s1[g] + v.w) - 2.f*((qx[g]*v.x + qy[g]*v.y) + qz[g]*v.z);
        m[g] = fminf(m[g], d);
      }
    }
  }
  // kappa[g] = 17th smallest lane-min (> true d16: at most 16 lane-minima can be <= d16)
  #pragma unroll
  for (int g = 0; g < 4; g++) {
    float v = m[g];
    #pragma unroll
    for (int k = 2; k <= 64; k <<= 1) {
      #pragma unroll
      for (int j = k >> 1; j > 0; j >>= 1) {
        const float pv = __shfl_xor(v, j);
        const bool up = ((lane & k) == 0);
        const bool keepmin = up ? ((lane & j) == 0) : ((lane & j) != 0);
        v = keepmin ? fminf(v, pv) : fmaxf(v, pv);
      }
    }
    kappa[g] = __shfl(v, 16);
  }

  // ---- pass 2: exact streaming insert, ballot gated by min(kth, kappa) ----
  float listd = INFINITY; int listi = 0;
  for (int t0 = 0; t0 < N2S; t0 += KTILE) {
    __syncthreads();
    for (int i = tid; i < KTILE; i += 256) T[i] = X[t0 + i];
    __syncthreads();
    for (int c0 = 0; c0 < KTILE; c0 += 64) {
      const float4 v = T[c0 + lane];
      #pragma unroll
      for (int g = 0; g < 4; g++) {
        // EXACT same distance expression as pass 1 / r3
        const float d = (s1[g] + v.w) - 2.f*((qx[g]*v.x + qy[g]*v.y) + qz[g]*v.z);
        unsigned long long vote = __ballot(d < fminf(kth[g], kappa[g]));
        while (vote) {
          const int src = (int)__builtin_ctzll(vote);
          vote &= vote - 1;
          const float dv = __shfl(d, src);
          if (dv < kth[g]) {                       // uniform
            const int iv = t0 + c0 + src;
            const float ud = __shfl_up(listd, 1);
            const int   ui = __shfl_up(listi, 1);
            const bool ing = (grp == g);
            const bool cm = ing && (dv < listd);   // strict < keeps lower index on ties
            const bool cp = cm && ((lane & 15) > 0) && (dv < ud);
            listd = cm ? (cp ? ud : dv) : listd;
            listi = cm ? (cp ? ui : iv) : listi;
            kth[g] = __shfl(listd, g*16 + 15);
          }
        }
      }
    }
  }

  // ---- exactness guard: if <16 found (kth stayed INF), rescan that query unpruned ----
  {
    bool need = false;
    #pragma unroll
    for (int g = 0; g < 4; g++) need = need || (kth[g] == INFINITY);
    if (__builtin_expect(need, 0)) {
      #pragma unroll
      for (int g = 0; g < 4; g++) {
        if (kth[g] == INFINITY) {                  // uniform
          if (grp == g) { listd = INFINITY; listi = 0; }
          float kk2 = INFINITY;
          for (int c0 = 0; c0 < N2S; c0 += 64) {
            const float4 v = X[c0 + lane];
            const float d = (s1[g] + v.w) - 2.f*((qx[g]*v.x + qy[g]*v.y) + qz[g]*v.z);
            unsigned long long vote = __ballot(d < kk2);
            while (vote) {
              const int src = (int)__builtin_ctzll(vote);
              vote &= vote - 1;
              const float dv = __shfl(d, src);
              if (dv < kk2) {
                const int iv = c0 + src;
                const float ud = __shfl_up(listd, 1);
                const int   ui = __shfl_up(listi, 1);
                const bool ing = (grp == g);
                const bool cm = ing && (dv < listd);
                const bool cp = cm && ((lane & 15) > 0) && (dv < ud);
                listd = cm ? (cp ? ud : dv) : listd;
                listi = cm ? (cp ? ui : iv) : listi;
                kk2 = __shfl(listd, g*16 + 15);
              }
            }
          }
        }
      }
    }
  }
  idxout[(size_t)(qbase + grp)*KK + (lane & 15)] = listi;
}

// ---------------- gates: MFMA pipeline, 8 queries / block, 4 waves = 4 row-tiles ----------------
#define FRAG(mat, kk) (*(const bf8_t*)(wA + (((mat)*4 + w)*2 + (kk))*512 + lane*8))

__global__ __launch_bounds__(256) void gates_kernel(
    const float* __restrict__ xyz1, const float* __restrict__ xyz2,
    const float* __restrict__ points1, const unsigned short* __restrict__ p2b,
    const int* __restrict__ kidx, const short* __restrict__ wA,
    const float* __restrict__ wdir,
    const float* __restrict__ b_r0, const float* __restrict__ b_z0,
    const float* __restrict__ b_h0, const float* __restrict__ b_r1,
    const float* __restrict__ b_z1, const float* __restrict__ b_h1,
    float* __restrict__ out)
{
  __shared__ __align__(16) short featB[2][GQ][64][8];  // p2 channels, B-frag packed (16 KB)
  __shared__ __align__(16) short rB[2][GQ][64][8];     // r0 acts, then r*p1 in-place (16 KB)
  __shared__ __align__(16) float p1f[64][GQ];
  __shared__ __align__(16) short p1B[2][64][8];
  __shared__ float BFr[64][GQ], BFz[64][GQ];
  __shared__ float zmaxL[64][GQ], hmaxL[64][GQ];
  __shared__ float biasL[6][64];
  __shared__ float dirL[3][GQ*KK];
  __shared__ __align__(16) float obuf[64][GQ];

  const int tid = threadIdx.x;
  const int w = tid >> 6, lane = tid & 63;
  const int b  = blockIdx.x >> 9;
  const int n0 = (blockIdx.x & 511) * GQ;
  const int cq = lane & 15;                       // C col within tile (= query q)
  const int reg_o0 = w*16 + ((lane >> 4) << 2);   // first of this lane's 4 C rows
  const f32x4 zero4 = {0.f, 0.f, 0.f, 0.f};

  // ---- P0a ----
  for (int i = tid; i < 6*64; i += 256) {
    const int a = i >> 6, o = i & 63;
    const float* bp = (a==0)?b_r0:(a==1)?b_z0:(a==2)?b_h0:(a==3)?b_r1:(a==4)?b_z1:b_h1;
    biasL[a][o] = bp[o];
  }
  if (tid < 64) {
    const float* sp = points1 + ((size_t)(b*CC + tid))*N1S + n0;
    *(float4*)&p1f[tid][0] = ((const float4*)sp)[0];
    *(float4*)&p1f[tid][4] = ((const float4*)sp)[1];
  }
  ((unsigned long long*)&p1B[0][0][0])[tid] = 0ULL;   // zero 2048 B
  if (tid < 128) {                                    // dir channels
    const int m = tid, qg = n0 + (m >> 4);
    const int j = kidx[(size_t)((b << 12) + qg)*KK + (m & 15)];
    #pragma unroll
    for (int d = 0; d < 3; d++)
      dirL[d][m] = xyz2[((size_t)(b*3+d))*N2S + j] - xyz1[((size_t)(b*3+d))*N1S + qg];
  }
  {                                                   // p2 feature gather (bf16) -> featB (B-frag packed)
    const int m = tid >> 1, half = tid & 1;
    const int ct = m >> 4;
    const int qg = n0 + ct;
    const int j = kidx[(size_t)((b << 12) + qg)*KK + (m & 15)];
    const uint4* __restrict__ src = (const uint4*)(p2b + (((size_t)(b << 13) + j)*CC + half*32));
    #pragma unroll
    for (int gi = 0; gi < 4; gi++)
      *(uint4*)&featB[half][ct][gi*16 + (m & 15)][0] = src[gi];
  }
  __syncthreads();

  // ---- P0b: p1 as B-frag (cols 0..7 valid, rest zero) ----
  {
    const int s0 = tid*4;
    const int j0 = s0 & 7, l = (s0 >> 3) & 63, kk = s0 >> 9;
    const int q = l & 15;
    if (q < 8) {
      unsigned short t0[4];
      #pragma unroll
      for (int jj = 0; jj < 4; jj++)
        t0[jj] = f2bf(p1f[kk*32 + ((l >> 4) << 3) + j0 + jj][q]);
      uint2 pk; pk.x = t0[0] | ((unsigned)t0[1] << 16); pk.y = t0[2] | ((unsigned)t0[3] << 16);
      *(uint2*)&p1B[kk][l][j0] = pk;
    }
  }
  __syncthreads();

  // ---- P1: fuse GEMMs -> BFr/BFz ----
  {
    const bf8_t fa0 = FRAG(M_FR, 0), fa1 = FRAG(M_FR, 1);
    const bf8_t ga0 = FRAG(M_FZ, 0), ga1 = FRAG(M_FZ, 1);
    const bf8_t pb0 = *(const bf8_t*)&p1B[0][lane][0];
    const bf8_t pb1 = *(const bf8_t*)&p1B[1][lane][0];
    f32x4 ar = __builtin_amdgcn_mfma_f32_16x16x32_bf16(fa0, pb0, zero4, 0, 0, 0);
    ar = __builtin_amdgcn_mfma_f32_16x16x32_bf16(fa1, pb1, ar, 0, 0, 0);
    f32x4 az = __builtin_amdgcn_mfma_f32_16x16x32_bf16(ga0, pb0, zero4, 0, 0, 0);
    az = __builtin_amdgcn_mfma_f32_16x16x32_bf16(ga1, pb1, az, 0, 0, 0);
    if (cq < 8) {
      #pragma unroll
      for (int r2 = 0; r2 < 4; r2++) {
        const int o = reg_o0 + r2;
        BFr[o][cq] = ar[r2] + biasL[0][o];
        BFz[o][cq] = az[r2] + biasL[1][o];
      }
    }
  }

  // ---- P1b: layer-0 r/z (+dir epilogue), write r0 B-frags, z max-reduce ----
  {
    const bf8_t ra0 = FRAG(M_R0, 0), ra1 = FRAG(M_R0, 1);
    const bf8_t za0 = FRAG(M_Z0, 0), za1 = FRAG(M_Z0, 1);
    float wdr[3][4], wdz[3][4];
    #pragma unroll
    for (int d = 0; d < 3; d++)
      #pragma unroll
      for (int r2 = 0; r2 < 4; r2++) {
        wdr[d][r2] = wdir[(0*3 + d)*64 + reg_o0 + r2];
        wdz[d][r2] = wdir[(1*3 + d)*64 + reg_o0 + r2];
      }
    const int kkv = reg_o0 >> 5, lp = ((reg_o0 & 31) >> 3)*16 + cq, j0 = reg_o0 & 7;
    #pragma unroll
    for (int ct = 0; ct < GQ; ct++) {
      const bf8_t fb0 = *(const bf8_t*)&featB[0][ct][lane][0];
      const bf8_t fb1 = *(const bf8_t*)&featB[1][ct][lane][0];
      f32x4 accr = __builtin_amdgcn_mfma_f32_16x16x32_bf16(ra0, fb0, zero4, 0, 0, 0);
      accr = __builtin_amdgcn_mfma_f32_16x16x32_bf16(ra1, fb1, accr, 0, 0, 0);
      f32x4 accz = __builtin_amdgcn_mfma_f32_16x16x32_bf16(za0, fb0, zero4, 0, 0, 0);
      accz = __builtin_amdgcn_mfma_f32_16x16x32_bf16(za1, fb1, accz, 0, 0, 0);
      const int m = ct*16 + cq;
      const float d0 = dirL[0][m], d1 = dirL[1][m], d2 = dirL[2][m];
      unsigned short rpk[4]; float zv[4];
      #pragma unroll
      for (int r2 = 0; r2 < 4; r2++) {
        const int o = reg_o0 + r2;
        float rv = accr[r2] + BFr[o][ct] + wdr[0][r2]*d0 + wdr[1][r2]*d1 + wdr[2][r2]*d2;
        rpk[r2] = f2bf(lrelu(rv));
        float zt = accz[r2] + BFz[o][ct] + wdz[0][r2]*d0 + wdz[1][r2]*d1 + wdz[2][r2]*d2;
        zv[r2] = lrelu(zt);
      }
      uint2 pk; pk.x = rpk[0] | ((unsigned)rpk[1] << 16); pk.y = rpk[2] | ((unsigned)rpk[3] << 16);
      *(uint2*)&rB[kkv][ct][lp][j0] = pk;
      #pragma unroll
      for (int r2 = 0; r2 < 4; r2++) {
        float vv = zv[r2];
        vv = fmaxf(vv, __shfl_xor(vv, 1));
        vv = fmaxf(vv, __shfl_xor(vv, 2));
        vv = fmaxf(vv, __shfl_xor(vv, 4));
        vv = fmaxf(vv, __shfl_xor(vv, 8));
        zv[r2] = vv;
      }
      if (cq == 0) {
        #pragma unroll
        for (int r2 = 0; r2 < 4; r2++) zmaxL[reg_o0 + r2][ct] = zv[r2];
      }
    }
  }
  __syncthreads();

  // ---- P2: r1 (hold r*p1 packed in regs), z1 ----
  uint2 rpK[GQ];
  float zg[4];
  {
    const bf8_t r1a0 = FRAG(M_R1, 0), r1a1 = FRAG(M_R1, 1);
    #pragma unroll
    for (int ct = 0; ct < GQ; ct++) {
      const bf8_t b0 = *(const bf8_t*)&rB[0][ct][lane][0];
      const bf8_t b1 = *(const bf8_t*)&rB[1][ct][lane][0];
      f32x4 acc = __builtin_amdgcn_mfma_f32_16x16x32_bf16(r1a0, b0, zero4, 0, 0, 0);
      acc = __builtin_amdgcn_mfma_f32_16x16x32_bf16(r1a1, b1, acc, 0, 0, 0);
      unsigned short pk4[4];
      #pragma unroll
      for (int r2 = 0; r2 < 4; r2++) {
        const int o = reg_o0 + r2;
        const float rg = sigm(acc[r2] + biasL[3][o]);
        pk4[r2] = f2bf(rg * p1f[o][ct]);
      }
      rpK[ct].x = pk4[0] | ((unsigned)pk4[1] << 16);
      rpK[ct].y = pk4[2] | ((unsigned)pk4[3] << 16);
    }
    const bf8_t z1a0 = FRAG(M_Z1, 0), z1a1 = FRAG(M_Z1, 1);
    const int qc = cq < 8 ? cq : 7;
    bf8_t zb0, zb1;
    #pragma unroll
    for (int j = 0; j < 8; j++) {
      zb0[j] = (short)f2bf(zmaxL[((lane >> 4) << 3) + j][qc]);
      zb1[j] = (short)f2bf(zmaxL[32 + ((lane >> 4) << 3) + j][qc]);
    }
    f32x4 az = __builtin_amdgcn_mfma_f32_16x16x32_bf16(z1a0, zb0, zero4, 0, 0, 0);
    az = __builtin_amdgcn_mfma_f32_16x16x32_bf16(z1a1, zb1, az, 0, 0, 0);
    #pragma unroll
    for (int r2 = 0; r2 < 4; r2++) zg[r2] = sigm(az[r2] + biasL[4][reg_o0 + r2]);
  }
  __syncthreads();

  // ---- P2b: overwrite rB with r*p1 ----
  {
    const int kkv = reg_o0 >> 5, lp = ((reg_o0 & 31) >> 3)*16 + cq, j0 = reg_o0 & 7;
    #pragma unroll
    for (int ct = 0; ct < GQ; ct++) *(uint2*)&rB[kkv][ct][lp][j0] = rpK[ct];
  }
  __syncthreads();

  // ---- P3: h0·feat + fro·(r*p1) (+dir), h max-reduce ----
  {
    const bf8_t h0a0 = FRAG(M_H0, 0), h0a1 = FRAG(M_H0, 1);
    const bf8_t foa0 = FRAG(M_FRO, 0), foa1 = FRAG(M_FRO, 1);
    float wdh[3][4];
    #pragma unroll
    for (int d = 0; d < 3; d++)
      #pragma unroll
      for (int r2 = 0; r2 < 4; r2++) wdh[d][r2] = wdir[(2*3 + d)*64 + reg_o0 + r2];
    #pragma unroll
    for (int ct = 0; ct < GQ; ct++) {
      const bf8_t fb0 = *(const bf8_t*)&featB[0][ct][lane][0];
      const bf8_t fb1 = *(const bf8_t*)&featB[1][ct][lane][0];
      const bf8_t rb0 = *(const bf8_t*)&rB[0][ct][lane][0];
      const bf8_t rb1 = *(const bf8_t*)&rB[1][ct][lane][0];
      f32x4 acc = __builtin_amdgcn_mfma_f32_16x16x32_bf16(h0a0, fb0, zero4, 0, 0, 0);
      acc = __builtin_amdgcn_mfma_f32_16x16x32_bf16(h0a1, fb1, acc, 0, 0, 0);
      acc = __builtin_amdgcn_mfma_f32_16x16x32_bf16(foa0, rb0, acc, 0, 0, 0);
      acc = __builtin_amdgcn_mfma_f32_16x16x32_bf16(foa1, rb1, acc, 0, 0, 0);
      const int m = ct*16 + cq;
      const float d0 = dirL[0][m], d1 = dirL[1][m], d2 = dirL[2][m];
      float hv[4];
      #pragma unroll
      for (int r2 = 0; r2 < 4; r2++) {
        const int o = reg_o0 + r2;
        hv[r2] = lrelu(acc[r2] + biasL[2][o] + wdh[0][r2]*d0 + wdh[1][r2]*d1 + wdh[2][r2]*d2);
      }
      #pragma unroll
      for (int r2 = 0; r2 < 4; r2++) {
        float vv = hv[r2];
        vv = fmaxf(vv, __shfl_xor(vv, 1));
        vv = fmaxf(vv, __shfl_xor(vv, 2));
        vv = fmaxf(vv, __shfl_xor(vv, 4));
        vv = fmaxf(vv, __shfl_xor(vv, 8));
        hv[r2] = vv;
      }
      if (cq == 0) {
        #pragma unroll
        for (int r2 = 0; r2 < 4; r2++) hmaxL[reg_o0 + r2][ct] = hv[r2];
      }
    }
  }
  __syncthreads();

  // ---- P4: h1, final blend ----
  {
    const bf8_t h1a0 = FRAG(M_H1, 0), h1a1 = FRAG(M_H1, 1);
    const int qc = cq < 8 ? cq : 7;
    bf8_t hb0, hb1;
    #pragma unroll
    for (int j = 0; j < 8; j++) {
      hb0[j] = (short)f2bf(hmaxL[((lane >> 4) << 3) + j][qc]);
      hb1[j] = (short)f2bf(hmaxL[32 + ((lane >> 4) << 3) + j][qc]);
    }
    f32x4 ah = __builtin_amdgcn_mfma_f32_16x16x32_bf16(h1a0, hb0, zero4, 0, 0, 0);
    ah = __builtin_amdgcn_mfma_f32_16x16x32_bf16(h1a1, hb1, ah, 0, 0, 0);
    if (cq < 8) {
      #pragma unroll
      for (int r2 = 0; r2 < 4; r2++) {
        const int o = reg_o0 + r2;
        const float hg = tanh_(ah[r2] + biasL[5][o]);
        obuf[o][cq] = (1.f - zg[r2])*p1f[o][cq] + zg[r2]*hg;
      }
    }
  }
  __syncthreads();
  if (tid < 128) {
    const int c = tid >> 1, q4 = (tid & 1)*4;
    *(float4*)(out + ((size_t)(b*CC + c))*N1S + n0 + q4) = *(float4*)&obuf[c][q4];
  }
}

extern "C" void kernel_launch(void* const* d_in, const int* in_sizes, int n_in,
                              void* d_out, int out_size, void* d_ws, size_t ws_size,
                              hipStream_t stream) {
  const float* xyz1    = (const float*)d_in[0];
  const float* xyz2    = (const float*)d_in[1];
  const float* points1 = (const float*)d_in[2];
  const float* points2 = (const float*)d_in[3];
  const float* w_r0 = (const float*)d_in[4];
  const float* b_r0 = (const float*)d_in[5];
  const float* w_r1 = (const float*)d_in[6];
  const float* b_r1 = (const float*)d_in[7];
  const float* w_z0 = (const float*)d_in[8];
  const float* b_z0 = (const float*)d_in[9];
  const float* w_z1 = (const float*)d_in[10];
  const float* b_z1 = (const float*)d_in[11];
  const float* w_h0 = (const float*)d_in[12];
  const float* b_h0 = (const float*)d_in[13];
  const float* w_h1 = (const float*)d_in[14];
  const float* b_h1 = (const float*)d_in[15];
  const float* w_fr  = (const float*)d_in[16];
  const float* w_fz  = (const float*)d_in[17];
  const float* w_fro = (const float*)d_in[18];
  float* out = (float*)d_out;

  short*  wa   = (short*)d_ws;
  float*  wdir = (float*)((char*)d_ws + WDIR_OFF);
  float4* xp   = (float4*)((char*)d_ws + XP_OFF);
  int*    kidx = (int*)((char*)d_ws + KIDX_OFF);
  unsigned short* p2b = (unsigned short*)((char*)d_ws + P2B_OFF);

  prep_wA<<<16, 256, 0, stream>>>(w_r0, w_z0, w_h0, w_r1, w_z1, w_h1,
                                  w_fr, w_fz, w_fro, wa, wdir);
  pack_xyz2<<<64, 256, 0, stream>>>(xyz2, xp);
  transpose_p2<<<dim3(N2S/64, NB), dim3(256), 0, stream>>>(points2, p2b);

  knn_kernel<<<512, 256, 0, stream>>>(xyz1, xp, kidx);

  gates_kernel<<<1024, 256, 0, stream>>>(
      xyz1, xyz2, points1, p2b, kidx, wa, wdir,
      b_r0, b_z0, b_h0, b_r1, b_z1, b_h1, out);
}